// Round 2
// baseline (2555.914 us; speedup 1.0000x reference)
//
#include <hip/hip_runtime.h>

#define TD 256  // feature dimension (D_IN == D_OUT == 256)

// ---------------------------------------------------------------------------
// agg[dst] += x[src]  -- one wave (64 lanes) per edge, float4 per lane.
// ---------------------------------------------------------------------------
__global__ __launch_bounds__(256) void scatter_x_kernel(
    const float* __restrict__ x, const int* __restrict__ ei, int E,
    float* __restrict__ agg) {
  int wid = blockIdx.x * 4 + (threadIdx.x >> 6);
  if (wid >= E) return;
  int lane = threadIdx.x & 63;
  int src = ei[wid];
  int dst = ei[E + wid];
  const float4 xv =
      *reinterpret_cast<const float4*>(x + (size_t)src * TD + lane * 4);
  float* a = agg + (size_t)dst * TD + lane * 4;
  atomicAdd(a + 0, xv.x);
  atomicAdd(a + 1, xv.y);
  atomicAdd(a + 2, xv.z);
  atomicAdd(a + 3, xv.w);
}

// ---------------------------------------------------------------------------
// Per-edge attention: attn = dot(q[d], k[s]) over 256 dims (wave allreduce),
// then out[d] -= attn * v[s].
// ---------------------------------------------------------------------------
__global__ __launch_bounds__(256) void attn_edge_kernel(
    const float* __restrict__ q, const float* __restrict__ k,
    const float* __restrict__ v, const int* __restrict__ ei2, int E,
    float* __restrict__ out) {
  int wid = blockIdx.x * 4 + (threadIdx.x >> 6);
  if (wid >= E) return;
  int lane = threadIdx.x & 63;
  int s = ei2[wid];       // source
  int d = ei2[E + wid];   // destination
  const float4 qv =
      *reinterpret_cast<const float4*>(q + (size_t)d * TD + lane * 4);
  const float4 kv =
      *reinterpret_cast<const float4*>(k + (size_t)s * TD + lane * 4);
  float p = qv.x * kv.x + qv.y * kv.y + qv.z * kv.z + qv.w * kv.w;
#pragma unroll
  for (int m = 1; m < 64; m <<= 1) p += __shfl_xor(p, m, 64);
  const float4 vv =
      *reinterpret_cast<const float4*>(v + (size_t)s * TD + lane * 4);
  float* o = out + (size_t)d * TD + lane * 4;
  atomicAdd(o + 0, -p * vv.x);
  atomicAdd(o + 1, -p * vv.y);
  atomicAdd(o + 2, -p * vv.z);
  atomicAdd(o + 3, -p * vv.w);
}

// ---------------------------------------------------------------------------
// C[M,256] (+)= A[M,256] @ B[256,256], fp32, BM=BN=128, BK=16,
// 256 threads, 8x8 register tile per thread.
// ---------------------------------------------------------------------------
template <bool ACCUM>
__global__ __launch_bounds__(256) void gemm_k256(
    const float* __restrict__ A, const float* __restrict__ B,
    float* __restrict__ C, int M) {
  __shared__ float As[16][132];  // As[kk][row]  (A tile transposed)
  __shared__ float Bs[16][132];  // Bs[kk][col]

  const int tid = threadIdx.x;
  const int tx = tid & 15;   // 0..15  -> col group
  const int ty = tid >> 4;   // 0..15  -> row group
  const int m0 = blockIdx.x * 128;
  const int n0 = blockIdx.y * 128;

  float acc[8][8];
#pragma unroll
  for (int i = 0; i < 8; i++)
#pragma unroll
    for (int j = 0; j < 8; j++) acc[i][j] = 0.0f;

  for (int k0 = 0; k0 < TD; k0 += 16) {
    // --- load A tile (128 rows x 16 cols), store transposed ---
#pragma unroll
    for (int i = 0; i < 2; i++) {
      int t = tid + i * 256;      // 0..511
      int row = t >> 2;           // 0..127
      int seg = t & 3;            // 4 floats each
      float4 a = make_float4(0.f, 0.f, 0.f, 0.f);
      if (m0 + row < M)
        a = *reinterpret_cast<const float4*>(A + (size_t)(m0 + row) * TD + k0 +
                                             seg * 4);
      As[seg * 4 + 0][row] = a.x;
      As[seg * 4 + 1][row] = a.y;
      As[seg * 4 + 2][row] = a.z;
      As[seg * 4 + 3][row] = a.w;
    }
    // --- load B tile (16 rows x 128 cols) ---
#pragma unroll
    for (int i = 0; i < 2; i++) {
      int t = tid + i * 256;      // 0..511
      int kk = t >> 5;            // 0..15
      int seg = t & 31;           // 32 segs * 4 floats = 128 cols
      float4 b = *reinterpret_cast<const float4*>(B + (size_t)(k0 + kk) * TD +
                                                  n0 + seg * 4);
      *reinterpret_cast<float4*>(&Bs[kk][seg * 4]) = b;
    }
    __syncthreads();

#pragma unroll
    for (int kk = 0; kk < 16; kk++) {
      float a[8], b[8];
      *reinterpret_cast<float4*>(&a[0]) =
          *reinterpret_cast<const float4*>(&As[kk][ty * 8]);
      *reinterpret_cast<float4*>(&a[4]) =
          *reinterpret_cast<const float4*>(&As[kk][ty * 8 + 4]);
      *reinterpret_cast<float4*>(&b[0]) =
          *reinterpret_cast<const float4*>(&Bs[kk][tx * 8]);
      *reinterpret_cast<float4*>(&b[4]) =
          *reinterpret_cast<const float4*>(&Bs[kk][tx * 8 + 4]);
#pragma unroll
      for (int i = 0; i < 8; i++)
#pragma unroll
        for (int j = 0; j < 8; j++) acc[i][j] = fmaf(a[i], b[j], acc[i][j]);
    }
    __syncthreads();
  }

  // --- store ---
#pragma unroll
  for (int i = 0; i < 8; i++) {
    int row = m0 + ty * 8 + i;
    if (row >= M) continue;
    float* cp = C + (size_t)row * TD + n0 + tx * 8;
    if (ACCUM) {
      float4 c0 = *reinterpret_cast<float4*>(cp);
      float4 c1 = *reinterpret_cast<float4*>(cp + 4);
      c0.x += acc[i][0]; c0.y += acc[i][1]; c0.z += acc[i][2]; c0.w += acc[i][3];
      c1.x += acc[i][4]; c1.y += acc[i][5]; c1.z += acc[i][6]; c1.w += acc[i][7];
      *reinterpret_cast<float4*>(cp) = c0;
      *reinterpret_cast<float4*>(cp + 4) = c1;
    } else {
      float4 c0 = make_float4(acc[i][0], acc[i][1], acc[i][2], acc[i][3]);
      float4 c1 = make_float4(acc[i][4], acc[i][5], acc[i][6], acc[i][7]);
      *reinterpret_cast<float4*>(cp) = c0;
      *reinterpret_cast<float4*>(cp + 4) = c1;
    }
  }
}

extern "C" void kernel_launch(void* const* d_in, const int* in_sizes, int n_in,
                              void* d_out, int out_size, void* d_ws,
                              size_t ws_size, hipStream_t stream) {
  const float* x  = (const float*)d_in[0];
  const int*   ei  = (const int*)d_in[1];
  const int*   ei2 = (const int*)d_in[2];
  const float* W0 = (const float*)d_in[3];
  const float* W1 = (const float*)d_in[4];
  const float* Wq = (const float*)d_in[5];
  const float* Wk = (const float*)d_in[6];
  const float* Wv = (const float*)d_in[7];

  const int N  = in_sizes[0] / TD;
  const int E1 = in_sizes[1] / 2;
  const int E2 = in_sizes[2] / 2;

  float* out = (float*)d_out;
  const size_t buf = (size_t)N * TD;
  float* ws = (float*)d_ws;
  float* agg = ws;            // [N,256]; dead after agg@W1, reused for q
  float* q   = ws;            // aliases agg (safe: stream-ordered)
  float* k   = ws + buf;
  float* v   = ws + 2 * buf;

  // 1. agg = segment_sum(x[src], dst)
  hipMemsetAsync(agg, 0, buf * sizeof(float), stream);
  scatter_x_kernel<<<(E1 + 3) / 4, 256, 0, stream>>>(x, ei, E1, agg);

  // 2. out = x@W0 + agg@W1
  dim3 grid((N + 127) / 128, TD / 128);
  gemm_k256<false><<<grid, 256, 0, stream>>>(x, W0, out, N);
  gemm_k256<true><<<grid, 256, 0, stream>>>(agg, W1, out, N);

  // 3. q,k,v = x @ {Wq, Wk, Wv}   (q overwrites agg region -- agg is dead)
  gemm_k256<false><<<grid, 256, 0, stream>>>(x, Wq, q, N);
  gemm_k256<false><<<grid, 256, 0, stream>>>(x, Wk, k, N);
  gemm_k256<false><<<grid, 256, 0, stream>>>(x, Wv, v, N);

  // 4. out -= scatter(attn * v[src], dst)
  attn_edge_kernel<<<(E2 + 3) / 4, 256, 0, stream>>>(q, k, v, ei2, E2, out);
}

// Round 3
// 845.703 us; speedup vs baseline: 3.0222x; 3.0222x over previous
//
#include <hip/hip_runtime.h>

#define TD 256  // feature dimension (D_IN == D_OUT == 256)

// ===========================================================================
// CSR-построение: histogram -> exclusive scan -> fill
// ===========================================================================
__global__ __launch_bounds__(256) void hist_kernel(
    const int* __restrict__ ei, int E1, const int* __restrict__ ei2, int E2,
    int* __restrict__ deg1, int* __restrict__ deg2) {
  int stride = gridDim.x * blockDim.x;
  int Emax = max(E1, E2);
  for (int i = blockIdx.x * blockDim.x + threadIdx.x; i < Emax; i += stride) {
    if (i < E1) atomicAdd(&deg1[ei[E1 + i]], 1);
    if (i < E2) atomicAdd(&deg2[ei2[E2 + i]], 1);
  }
}

// One block per array (grid.x==2). 1024 threads, chunked scan over N.
__global__ __launch_bounds__(1024) void scan_kernel(
    const int* __restrict__ deg1, int* __restrict__ off1, int* __restrict__ cur1,
    const int* __restrict__ deg2, int* __restrict__ off2, int* __restrict__ cur2,
    int N) {
  const int* deg = blockIdx.x == 0 ? deg1 : deg2;
  int* off = blockIdx.x == 0 ? off1 : off2;
  int* cur = blockIdx.x == 0 ? cur1 : cur2;

  __shared__ int part[1024];
  const int t = threadIdx.x;
  const int CH = (N + 1023) / 1024;
  const int beg = t * CH;
  const int end = min(beg + CH, N);
  int s = 0;
  for (int i = beg; i < end; i++) s += deg[i];
  part[t] = s;
  __syncthreads();
  // inclusive Hillis-Steele scan over 1024 partials
  for (int d = 1; d < 1024; d <<= 1) {
    int val = (t >= d) ? part[t - d] : 0;
    __syncthreads();
    part[t] += val;
    __syncthreads();
  }
  int run = part[t] - s;  // exclusive prefix of this chunk
  for (int i = beg; i < end; i++) {
    off[i] = run;
    cur[i] = run;
    run += deg[i];
  }
  if (t == 1023) off[N] = part[1023];
}

__global__ __launch_bounds__(256) void fill_kernel(
    const int* __restrict__ ei, int E1, const int* __restrict__ ei2, int E2,
    int* __restrict__ cur1, int* __restrict__ cur2,
    int* __restrict__ csr1, int* __restrict__ csr2) {
  int stride = gridDim.x * blockDim.x;
  int Emax = max(E1, E2);
  for (int i = blockIdx.x * blockDim.x + threadIdx.x; i < Emax; i += stride) {
    if (i < E1) {
      int d = ei[E1 + i];
      int p = atomicAdd(&cur1[d], 1);
      csr1[p] = ei[i];  // src
    }
    if (i < E2) {
      int d = ei2[E2 + i];
      int p = atomicAdd(&cur2[d], 1);
      csr2[p] = ei2[i];  // src
    }
  }
}

// ===========================================================================
// Gather branch 1: agg[n] = sum_{e: dst=n} x[src_e].  One wave per node.
// ===========================================================================
__global__ __launch_bounds__(256) void gather_x_kernel(
    const float* __restrict__ x, const int* __restrict__ off,
    const int* __restrict__ csr, int N, float* __restrict__ agg) {
  int wid = blockIdx.x * 4 + (threadIdx.x >> 6);
  if (wid >= N) return;
  int lane = threadIdx.x & 63;
  int beg = off[wid], end = off[wid + 1];
  float4 acc = make_float4(0.f, 0.f, 0.f, 0.f);
  for (int j = beg; j < end; j++) {
    int s = csr[j];
    float4 xv = *reinterpret_cast<const float4*>(x + (size_t)s * TD + lane * 4);
    acc.x += xv.x; acc.y += xv.y; acc.z += xv.z; acc.w += xv.w;
  }
  *reinterpret_cast<float4*>(agg + (size_t)wid * TD + lane * 4) = acc;
}

// ===========================================================================
// Gather branch 2: out[n] -= sum_{e: d=n} (q[n].k[s_e]) * v[s_e].
// One wave per node; q row in registers, score via wave allreduce.
// ===========================================================================
__global__ __launch_bounds__(256) void gather_attn_kernel(
    const float* __restrict__ q, const float* __restrict__ k,
    const float* __restrict__ v, const int* __restrict__ off,
    const int* __restrict__ csr, int N, float* __restrict__ out) {
  int wid = blockIdx.x * 4 + (threadIdx.x >> 6);
  if (wid >= N) return;
  int lane = threadIdx.x & 63;
  const float4 qv =
      *reinterpret_cast<const float4*>(q + (size_t)wid * TD + lane * 4);
  float* op = out + (size_t)wid * TD + lane * 4;
  float4 acc = *reinterpret_cast<const float4*>(op);
  int beg = off[wid], end = off[wid + 1];
  for (int j = beg; j < end; j++) {
    int s = csr[j];
    const float4 kv =
        *reinterpret_cast<const float4*>(k + (size_t)s * TD + lane * 4);
    float p = qv.x * kv.x + qv.y * kv.y + qv.z * kv.z + qv.w * kv.w;
#pragma unroll
    for (int m = 1; m < 64; m <<= 1) p += __shfl_xor(p, m, 64);
    const float4 vv =
        *reinterpret_cast<const float4*>(v + (size_t)s * TD + lane * 4);
    acc.x -= p * vv.x; acc.y -= p * vv.y; acc.z -= p * vv.z; acc.w -= p * vv.w;
  }
  *reinterpret_cast<float4*>(op) = acc;
}

// ===========================================================================
// Fallback atomic scatter kernels (used only if ws_size too small for CSR)
// ===========================================================================
__global__ __launch_bounds__(256) void scatter_x_kernel(
    const float* __restrict__ x, const int* __restrict__ ei, int E,
    float* __restrict__ agg) {
  int wid = blockIdx.x * 4 + (threadIdx.x >> 6);
  if (wid >= E) return;
  int lane = threadIdx.x & 63;
  int src = ei[wid];
  int dst = ei[E + wid];
  const float4 xv =
      *reinterpret_cast<const float4*>(x + (size_t)src * TD + lane * 4);
  float* a = agg + (size_t)dst * TD + lane * 4;
  atomicAdd(a + 0, xv.x);
  atomicAdd(a + 1, xv.y);
  atomicAdd(a + 2, xv.z);
  atomicAdd(a + 3, xv.w);
}

__global__ __launch_bounds__(256) void attn_edge_kernel(
    const float* __restrict__ q, const float* __restrict__ k,
    const float* __restrict__ v, const int* __restrict__ ei2, int E,
    float* __restrict__ out) {
  int wid = blockIdx.x * 4 + (threadIdx.x >> 6);
  if (wid >= E) return;
  int lane = threadIdx.x & 63;
  int s = ei2[wid];
  int d = ei2[E + wid];
  const float4 qv =
      *reinterpret_cast<const float4*>(q + (size_t)d * TD + lane * 4);
  const float4 kv =
      *reinterpret_cast<const float4*>(k + (size_t)s * TD + lane * 4);
  float p = qv.x * kv.x + qv.y * kv.y + qv.z * kv.z + qv.w * kv.w;
#pragma unroll
  for (int m = 1; m < 64; m <<= 1) p += __shfl_xor(p, m, 64);
  const float4 vv =
      *reinterpret_cast<const float4*>(v + (size_t)s * TD + lane * 4);
  float* o = out + (size_t)d * TD + lane * 4;
  atomicAdd(o + 0, -p * vv.x);
  atomicAdd(o + 1, -p * vv.y);
  atomicAdd(o + 2, -p * vv.z);
  atomicAdd(o + 3, -p * vv.w);
}

// ===========================================================================
// C[M,256] (+)= A[M,256] @ B[256,256], fp32, BM=BN=128, BK=16,
// 256 threads, 8x8 register tile per thread.
// ===========================================================================
template <bool ACCUM>
__global__ __launch_bounds__(256) void gemm_k256(
    const float* __restrict__ A, const float* __restrict__ B,
    float* __restrict__ C, int M) {
  __shared__ float As[16][132];  // As[kk][row]  (A tile transposed)
  __shared__ float Bs[16][132];  // Bs[kk][col]

  const int tid = threadIdx.x;
  const int tx = tid & 15;
  const int ty = tid >> 4;
  const int m0 = blockIdx.x * 128;
  const int n0 = blockIdx.y * 128;

  float acc[8][8];
#pragma unroll
  for (int i = 0; i < 8; i++)
#pragma unroll
    for (int j = 0; j < 8; j++) acc[i][j] = 0.0f;

  for (int k0 = 0; k0 < TD; k0 += 16) {
#pragma unroll
    for (int i = 0; i < 2; i++) {
      int t = tid + i * 256;
      int row = t >> 2;
      int seg = t & 3;
      float4 a = make_float4(0.f, 0.f, 0.f, 0.f);
      if (m0 + row < M)
        a = *reinterpret_cast<const float4*>(A + (size_t)(m0 + row) * TD + k0 +
                                             seg * 4);
      As[seg * 4 + 0][row] = a.x;
      As[seg * 4 + 1][row] = a.y;
      As[seg * 4 + 2][row] = a.z;
      As[seg * 4 + 3][row] = a.w;
    }
#pragma unroll
    for (int i = 0; i < 2; i++) {
      int t = tid + i * 256;
      int kk = t >> 5;
      int seg = t & 31;
      float4 b = *reinterpret_cast<const float4*>(B + (size_t)(k0 + kk) * TD +
                                                  n0 + seg * 4);
      *reinterpret_cast<float4*>(&Bs[kk][seg * 4]) = b;
    }
    __syncthreads();

#pragma unroll
    for (int kk = 0; kk < 16; kk++) {
      float a[8], b[8];
      *reinterpret_cast<float4*>(&a[0]) =
          *reinterpret_cast<const float4*>(&As[kk][ty * 8]);
      *reinterpret_cast<float4*>(&a[4]) =
          *reinterpret_cast<const float4*>(&As[kk][ty * 8 + 4]);
      *reinterpret_cast<float4*>(&b[0]) =
          *reinterpret_cast<const float4*>(&Bs[kk][tx * 8]);
      *reinterpret_cast<float4*>(&b[4]) =
          *reinterpret_cast<const float4*>(&Bs[kk][tx * 8 + 4]);
#pragma unroll
      for (int i = 0; i < 8; i++)
#pragma unroll
        for (int j = 0; j < 8; j++) acc[i][j] = fmaf(a[i], b[j], acc[i][j]);
    }
    __syncthreads();
  }

#pragma unroll
  for (int i = 0; i < 8; i++) {
    int row = m0 + ty * 8 + i;
    if (row >= M) continue;
    float* cp = C + (size_t)row * TD + n0 + tx * 8;
    if (ACCUM) {
      float4 c0 = *reinterpret_cast<float4*>(cp);
      float4 c1 = *reinterpret_cast<float4*>(cp + 4);
      c0.x += acc[i][0]; c0.y += acc[i][1]; c0.z += acc[i][2]; c0.w += acc[i][3];
      c1.x += acc[i][4]; c1.y += acc[i][5]; c1.z += acc[i][6]; c1.w += acc[i][7];
      *reinterpret_cast<float4*>(cp) = c0;
      *reinterpret_cast<float4*>(cp + 4) = c1;
    } else {
      float4 c0 = make_float4(acc[i][0], acc[i][1], acc[i][2], acc[i][3]);
      float4 c1 = make_float4(acc[i][4], acc[i][5], acc[i][6], acc[i][7]);
      *reinterpret_cast<float4*>(cp) = c0;
      *reinterpret_cast<float4*>(cp + 4) = c1;
    }
  }
}

extern "C" void kernel_launch(void* const* d_in, const int* in_sizes, int n_in,
                              void* d_out, int out_size, void* d_ws,
                              size_t ws_size, hipStream_t stream) {
  const float* x  = (const float*)d_in[0];
  const int*   ei  = (const int*)d_in[1];
  const int*   ei2 = (const int*)d_in[2];
  const float* W0 = (const float*)d_in[3];
  const float* W1 = (const float*)d_in[4];
  const float* Wq = (const float*)d_in[5];
  const float* Wk = (const float*)d_in[6];
  const float* Wv = (const float*)d_in[7];

  const int N  = in_sizes[0] / TD;
  const int E1 = in_sizes[1] / 2;
  const int E2 = in_sizes[2] / 2;

  float* out = (float*)d_out;
  const size_t buf = (size_t)N * TD;
  float* ws = (float*)d_ws;
  float* agg = ws;  // aliases q (agg dead before q written)
  float* q   = ws;
  float* k   = ws + buf;
  float* v   = ws + 2 * buf;

  // CSR int arrays after the 3 float buffers
  int* ip   = (int*)(ws + 3 * buf);
  int* off1 = ip;               // N+1
  int* cur1 = off1 + N + 1;     // N
  int* off2 = cur1 + N;         // N+1
  int* cur2 = off2 + N + 1;     // N
  int* csr1 = cur2 + N;         // E1
  int* csr2 = csr1 + E1;        // E2
  int* deg1 = csr2 + E2;        // N
  int* deg2 = deg1 + N;         // N

  const size_t need =
      3 * buf * sizeof(float) +
      ((size_t)6 * N + 2 + E1 + E2) * sizeof(int);

  dim3 grid((N + 127) / 128, TD / 128);

  if (ws_size >= need) {
    // ---- CSR path: no float atomics ----
    hipMemsetAsync(deg1, 0, (size_t)2 * N * sizeof(int), stream);
    hist_kernel<<<1024, 256, 0, stream>>>(ei, E1, ei2, E2, deg1, deg2);
    scan_kernel<<<2, 1024, 0, stream>>>(deg1, off1, cur1, deg2, off2, cur2, N);
    fill_kernel<<<1024, 256, 0, stream>>>(ei, E1, ei2, E2, cur1, cur2, csr1,
                                          csr2);
    // agg = segment_sum(x[src], dst)
    gather_x_kernel<<<(N + 3) / 4, 256, 0, stream>>>(x, off1, csr1, N, agg);
    // out = x@W0 + agg@W1
    gemm_k256<false><<<grid, 256, 0, stream>>>(x, W0, out, N);
    gemm_k256<true><<<grid, 256, 0, stream>>>(agg, W1, out, N);
    // q,k,v (q overwrites agg region -- agg dead)
    gemm_k256<false><<<grid, 256, 0, stream>>>(x, Wq, q, N);
    gemm_k256<false><<<grid, 256, 0, stream>>>(x, Wk, k, N);
    gemm_k256<false><<<grid, 256, 0, stream>>>(x, Wv, v, N);
    // out -= gather(score * v)
    gather_attn_kernel<<<(N + 3) / 4, 256, 0, stream>>>(q, k, v, off2, csr2, N,
                                                        out);
  } else {
    // ---- fallback: atomic scatter path ----
    hipMemsetAsync(agg, 0, buf * sizeof(float), stream);
    scatter_x_kernel<<<(E1 + 3) / 4, 256, 0, stream>>>(x, ei, E1, agg);
    gemm_k256<false><<<grid, 256, 0, stream>>>(x, W0, out, N);
    gemm_k256<true><<<grid, 256, 0, stream>>>(agg, W1, out, N);
    gemm_k256<false><<<grid, 256, 0, stream>>>(x, Wq, q, N);
    gemm_k256<false><<<grid, 256, 0, stream>>>(x, Wk, k, N);
    gemm_k256<false><<<grid, 256, 0, stream>>>(x, Wv, v, N);
    attn_edge_kernel<<<(E2 + 3) / 4, 256, 0, stream>>>(q, k, v, ei2, E2, out);
  }
}

// Round 4
// 390.213 us; speedup vs baseline: 6.5500x; 2.1673x over previous
//
#include <hip/hip_runtime.h>

#define TD 256  // feature dim

typedef __attribute__((ext_vector_type(8))) short short8;
typedef __attribute__((ext_vector_type(8))) unsigned short ushort8;
typedef __attribute__((ext_vector_type(4))) float f32x4;

__device__ inline unsigned short f2bf(float f) {
  unsigned u = __float_as_uint(f);
  u = u + 0x7fffu + ((u >> 16) & 1u);  // round-to-nearest-even
  return (unsigned short)(u >> 16);
}
__device__ inline float bf2f(unsigned short h) {
  return __uint_as_float(((unsigned)h) << 16);
}

// ===========================================================================
// CSR build: histogram -> scan -> fill
// ===========================================================================
__global__ __launch_bounds__(256) void hist_kernel(
    const int* __restrict__ ei, int E1, const int* __restrict__ ei2, int E2,
    int* __restrict__ deg1, int* __restrict__ deg2) {
  int stride = gridDim.x * blockDim.x;
  int Emax = max(E1, E2);
  for (int i = blockIdx.x * blockDim.x + threadIdx.x; i < Emax; i += stride) {
    if (i < E1) atomicAdd(&deg1[ei[E1 + i]], 1);
    if (i < E2) atomicAdd(&deg2[ei2[E2 + i]], 1);
  }
}

__global__ __launch_bounds__(1024) void scan_kernel(
    const int* __restrict__ deg1, int* __restrict__ off1, int* __restrict__ cur1,
    const int* __restrict__ deg2, int* __restrict__ off2, int* __restrict__ cur2,
    int N) {
  const int* deg = blockIdx.x == 0 ? deg1 : deg2;
  int* off = blockIdx.x == 0 ? off1 : off2;
  int* cur = blockIdx.x == 0 ? cur1 : cur2;

  __shared__ int part[1024];
  const int t = threadIdx.x;
  const int CH = (N + 1023) / 1024;
  const int beg = t * CH;
  const int end = min(beg + CH, N);
  int s = 0;
  for (int i = beg; i < end; i++) s += deg[i];
  part[t] = s;
  __syncthreads();
  for (int d = 1; d < 1024; d <<= 1) {
    int val = (t >= d) ? part[t - d] : 0;
    __syncthreads();
    part[t] += val;
    __syncthreads();
  }
  int run = part[t] - s;
  for (int i = beg; i < end; i++) {
    off[i] = run;
    cur[i] = run;
    run += deg[i];
  }
  if (t == 1023) off[N] = part[1023];
}

__global__ __launch_bounds__(256) void fill_kernel(
    const int* __restrict__ ei, int E1, const int* __restrict__ ei2, int E2,
    int* __restrict__ cur1, int* __restrict__ cur2,
    int* __restrict__ csr1, int* __restrict__ csr2) {
  int stride = gridDim.x * blockDim.x;
  int Emax = max(E1, E2);
  for (int i = blockIdx.x * blockDim.x + threadIdx.x; i < Emax; i += stride) {
    if (i < E1) {
      int d = ei[E1 + i];
      int p = atomicAdd(&cur1[d], 1);
      csr1[p] = ei[i];
    }
    if (i < E2) {
      int d = ei2[E2 + i];
      int p = atomicAdd(&cur2[d], 1);
      csr2[p] = ei2[i];
    }
  }
}

// ===========================================================================
// Conversions
// ===========================================================================
__global__ __launch_bounds__(256) void convert_x_kernel(
    const float* __restrict__ x, unsigned short* __restrict__ xb, long total8) {
  long t = (long)blockIdx.x * blockDim.x + threadIdx.x;
  if (t >= total8) return;
  const float4 f0 = *reinterpret_cast<const float4*>(x + t * 8);
  const float4 f1 = *reinterpret_cast<const float4*>(x + t * 8 + 4);
  ushort8 o;
  o[0] = f2bf(f0.x); o[1] = f2bf(f0.y); o[2] = f2bf(f0.z); o[3] = f2bf(f0.w);
  o[4] = f2bf(f1.x); o[5] = f2bf(f1.y); o[6] = f2bf(f1.z); o[7] = f2bf(f1.w);
  *reinterpret_cast<ushort8*>(xb + t * 8) = o;
}

// Bt[m][n][k] = W_m[k][n], bf16.  One block per (matrix, n) pair.
__global__ __launch_bounds__(256) void convert_w_kernel(
    const float* __restrict__ W0, const float* __restrict__ W1,
    const float* __restrict__ Wq, const float* __restrict__ Wk,
    const float* __restrict__ Wv, unsigned short* __restrict__ wt) {
  int m = blockIdx.x >> 8;
  int n = blockIdx.x & 255;
  int k = threadIdx.x;
  const float* W = m == 0 ? W0 : m == 1 ? W1 : m == 2 ? Wq : m == 3 ? Wk : Wv;
  wt[m * 65536 + n * 256 + k] = f2bf(W[k * 256 + n]);
}

// ===========================================================================
// agg[n] = sum_{e: dst=n} x[src_e]  (bf16 in, fp32 acc, bf16 out)
// One wave per node, lane handles 4 elems.
// ===========================================================================
__global__ __launch_bounds__(256) void gather_x_kernel(
    const unsigned short* __restrict__ xb, const int* __restrict__ off,
    const int* __restrict__ csr, int N, unsigned short* __restrict__ aggb) {
  int wid = blockIdx.x * 4 + (threadIdx.x >> 6);
  if (wid >= N) return;
  int lane = threadIdx.x & 63;
  int beg = off[wid], end = off[wid + 1];
  float ax = 0.f, ay = 0.f, az = 0.f, aw = 0.f;
  for (int j = beg; j < end; j++) {
    int s = csr[j];
    ushort4 xv = *reinterpret_cast<const ushort4*>(xb + (size_t)s * TD + lane * 4);
    ax += bf2f(xv.x); ay += bf2f(xv.y); az += bf2f(xv.z); aw += bf2f(xv.w);
  }
  ushort4 o;
  o.x = f2bf(ax); o.y = f2bf(ay); o.z = f2bf(az); o.w = f2bf(aw);
  *reinterpret_cast<ushort4*>(aggb + (size_t)wid * TD + lane * 4) = o;
}

// ===========================================================================
// out[n] -= sum_{e: d=n} (q[n].k[s_e]) * v[s_e]   (q,k,v bf16; out fp32)
// ===========================================================================
__global__ __launch_bounds__(256) void gather_attn_kernel(
    const unsigned short* __restrict__ qb, const unsigned short* __restrict__ kb,
    const unsigned short* __restrict__ vb, const int* __restrict__ off,
    const int* __restrict__ csr, int N, float* __restrict__ out) {
  int wid = blockIdx.x * 4 + (threadIdx.x >> 6);
  if (wid >= N) return;
  int lane = threadIdx.x & 63;
  ushort4 qv = *reinterpret_cast<const ushort4*>(qb + (size_t)wid * TD + lane * 4);
  float qx = bf2f(qv.x), qy = bf2f(qv.y), qz = bf2f(qv.z), qw = bf2f(qv.w);
  float* op = out + (size_t)wid * TD + lane * 4;
  float4 acc = *reinterpret_cast<const float4*>(op);
  int beg = off[wid], end = off[wid + 1];
  for (int j = beg; j < end; j++) {
    int s = csr[j];
    ushort4 kv = *reinterpret_cast<const ushort4*>(kb + (size_t)s * TD + lane * 4);
    float p = qx * bf2f(kv.x) + qy * bf2f(kv.y) + qz * bf2f(kv.z) + qw * bf2f(kv.w);
#pragma unroll
    for (int m = 1; m < 64; m <<= 1) p += __shfl_xor(p, m, 64);
    ushort4 vv = *reinterpret_cast<const ushort4*>(vb + (size_t)s * TD + lane * 4);
    acc.x -= p * bf2f(vv.x);
    acc.y -= p * bf2f(vv.y);
    acc.z -= p * bf2f(vv.z);
    acc.w -= p * bf2f(vv.w);
  }
  *reinterpret_cast<float4*>(op) = acc;
}

// ===========================================================================
// Fused MFMA GEMM.  grid = (8, ceil(M/128)).
//   sel = blockIdx.x; msel = sel>>1; n0 = (sel&1)*128; m0 = blockIdx.y*128
//   msel 0: out = [x | agg] @ [W0t ; W1t]   (K=512, fp32 out)
//   msel 1/2/3: q/k/v = x @ {Wqt,Wkt,Wvt}   (K=256, bf16 out)
// Tile 128x128, 4 waves (2x2 of 64x64), KSTEP=64, 16x16x32 bf16 MFMA.
// LDS staged via global_load_lds(16B) with XOR-(row&7) slot swizzle
// (pre-swizzled global source, linear LDS dest, swizzled ds_read).
// ===========================================================================
__global__ __launch_bounds__(256) void gemm_mfma(
    const unsigned short* __restrict__ xb, const unsigned short* __restrict__ aggb,
    const unsigned short* __restrict__ wt, float* __restrict__ out,
    unsigned short* __restrict__ qb, unsigned short* __restrict__ kb,
    unsigned short* __restrict__ vb, int M) {
  __shared__ __align__(16) unsigned short sA[128 * 64];
  __shared__ __align__(16) unsigned short sB[128 * 64];

  const int sel = blockIdx.x;
  const int msel = sel >> 1;
  const int n0 = (sel & 1) * 128;
  const int m0 = blockIdx.y * 128;

  const int tid = threadIdx.x;
  const int w = tid >> 6, l = tid & 63;
  const int lrow = l >> 3, lslot = l & 7;  // staging: 8 lanes/row, 8 slots/row
  const int wr = w >> 1, wc = w & 1;       // wave tile (64x64) coords

  f32x4 acc[4][4] = {};

  const int KTOT = (msel == 0) ? 512 : 256;

  for (int k0 = 0; k0 < KTOT; k0 += 64) {
    const unsigned short* Ap;
    const unsigned short* Bp;
    int ks;
    if (msel == 0) {
      if (k0 < 256) { Ap = xb;   Bp = wt;          ks = k0; }
      else          { Ap = aggb; Bp = wt + 65536;  ks = k0 - 256; }
    } else {
      Ap = xb; Bp = wt + (msel + 1) * 65536; ks = k0;
    }

    // ---- stage A tile [128][64] (rows m0..m0+127) ----
#pragma unroll
    for (int i = 0; i < 4; i++) {
      int row = w * 32 + i * 8 + lrow;          // row&7 == lrow
      int gr = m0 + row;
      if (gr >= M) gr = M - 1;                  // clamp (stores are guarded)
      int g = lslot ^ lrow;                     // inverse-swizzled k-group
      const unsigned short* src = Ap + (size_t)gr * TD + ks + g * 8;
      unsigned short* dst = sA + (w * 32 + i * 8) * 64;  // wave-uniform base
      __builtin_amdgcn_global_load_lds(
          (const __attribute__((address_space(1))) void*)src,
          (__attribute__((address_space(3))) void*)dst, 16, 0, 0);
    }
    // ---- stage B tile: Bt rows n0..n0+127 ----
#pragma unroll
    for (int i = 0; i < 4; i++) {
      int row = w * 32 + i * 8 + lrow;
      int g = lslot ^ lrow;
      const unsigned short* src = Bp + (size_t)(n0 + row) * TD + ks + g * 8;
      unsigned short* dst = sB + (w * 32 + i * 8) * 64;
      __builtin_amdgcn_global_load_lds(
          (const __attribute__((address_space(1))) void*)src,
          (__attribute__((address_space(3))) void*)dst, 16, 0, 0);
    }
    __syncthreads();

#pragma unroll
    for (int kk = 0; kk < 2; kk++) {
      short8 a[4], b[4];
#pragma unroll
      for (int m = 0; m < 4; m++) {
        int row = wr * 64 + m * 16 + (l & 15);
        int slot = (kk * 4 + (l >> 4)) ^ (row & 7);
        a[m] = *reinterpret_cast<const short8*>(&sA[row * 64 + slot * 8]);
      }
#pragma unroll
      for (int n = 0; n < 4; n++) {
        int row = wc * 64 + n * 16 + (l & 15);
        int slot = (kk * 4 + (l >> 4)) ^ (row & 7);
        b[n] = *reinterpret_cast<const short8*>(&sB[row * 64 + slot * 8]);
      }
#pragma unroll
      for (int m = 0; m < 4; m++)
#pragma unroll
        for (int n = 0; n < 4; n++)
          acc[m][n] =
              __builtin_amdgcn_mfma_f32_16x16x32_bf16(a[m], b[n], acc[m][n], 0, 0, 0);
    }
    __syncthreads();
  }

  // ---- store ----
  if (msel == 0) {
#pragma unroll
    for (int m = 0; m < 4; m++)
#pragma unroll
      for (int n = 0; n < 4; n++)
#pragma unroll
        for (int j = 0; j < 4; j++) {
          int r = m0 + wr * 64 + m * 16 + (l >> 4) * 4 + j;
          if (r < M)
            out[(size_t)r * TD + n0 + wc * 64 + n * 16 + (l & 15)] = acc[m][n][j];
        }
  } else {
    unsigned short* T = msel == 1 ? qb : msel == 2 ? kb : vb;
#pragma unroll
    for (int m = 0; m < 4; m++)
#pragma unroll
      for (int n = 0; n < 4; n++)
#pragma unroll
        for (int j = 0; j < 4; j++) {
          int r = m0 + wr * 64 + m * 16 + (l >> 4) * 4 + j;
          if (r < M)
            T[(size_t)r * TD + n0 + wc * 64 + n * 16 + (l & 15)] =
                f2bf(acc[m][n][j]);
        }
  }
}

// ===========================================================================
extern "C" void kernel_launch(void* const* d_in, const int* in_sizes, int n_in,
                              void* d_out, int out_size, void* d_ws,
                              size_t ws_size, hipStream_t stream) {
  const float* x  = (const float*)d_in[0];
  const int*   ei  = (const int*)d_in[1];
  const int*   ei2 = (const int*)d_in[2];
  const float* W0 = (const float*)d_in[3];
  const float* W1 = (const float*)d_in[4];
  const float* Wq = (const float*)d_in[5];
  const float* Wk = (const float*)d_in[6];
  const float* Wv = (const float*)d_in[7];

  const int N  = in_sizes[0] / TD;
  const int E1 = in_sizes[1] / 2;
  const int E2 = in_sizes[2] / 2;

  float* out = (float*)d_out;
  const size_t rowN = (size_t)N * TD;  // elements per [N,256] buffer

  // ---- workspace layout (bf16 buffers as ushort) ----
  char* p = (char*)d_ws;
  unsigned short* xb   = (unsigned short*)p; p += rowN * 2;
  unsigned short* aggb = (unsigned short*)p; p += rowN * 2;
  unsigned short* qb   = (unsigned short*)p; p += rowN * 2;
  unsigned short* kb   = (unsigned short*)p; p += rowN * 2;
  unsigned short* vb   = (unsigned short*)p; p += rowN * 2;
  unsigned short* wt   = (unsigned short*)p; p += 5 * 65536 * 2;
  int* off1 = (int*)p; p += (N + 1) * 4;
  int* cur1 = (int*)p; p += N * 4;
  int* off2 = (int*)p; p += (N + 1) * 4;
  int* cur2 = (int*)p; p += N * 4;
  int* csr1 = (int*)p; p += (size_t)E1 * 4;
  int* csr2 = (int*)p; p += (size_t)E2 * 4;
  int* deg1 = (int*)p; p += N * 4;
  int* deg2 = (int*)p; p += N * 4;

  // 1. CSR build
  hipMemsetAsync(deg1, 0, (size_t)2 * N * sizeof(int), stream);  // deg1+deg2
  hist_kernel<<<1024, 256, 0, stream>>>(ei, E1, ei2, E2, deg1, deg2);
  scan_kernel<<<2, 1024, 0, stream>>>(deg1, off1, cur1, deg2, off2, cur2, N);
  fill_kernel<<<1024, 256, 0, stream>>>(ei, E1, ei2, E2, cur1, cur2, csr1, csr2);

  // 2. conversions
  long total8 = rowN / 8;
  convert_x_kernel<<<(int)((total8 + 255) / 256), 256, 0, stream>>>(x, xb, total8);
  convert_w_kernel<<<5 * 256, 256, 0, stream>>>(W0, W1, Wq, Wk, Wv, wt);

  // 3. agg (bf16)
  gather_x_kernel<<<(N + 3) / 4, 256, 0, stream>>>(xb, off1, csr1, N, aggb);

  // 4. all five GEMMs in one dispatch
  dim3 grid(8, (N + 127) / 128);
  gemm_mfma<<<grid, 256, 0, stream>>>(xb, aggb, wt, out, qb, kb, vb, N);

  // 5. out -= gather(score * v)
  gather_attn_kernel<<<(N + 3) / 4, 256, 0, stream>>>(qb, kb, vb, off2, csr2, N, out);
}

// Round 5
// 287.850 us; speedup vs baseline: 8.8793x; 1.3556x over previous
//
#include <hip/hip_runtime.h>

#define TD 256  // feature dim

typedef __attribute__((ext_vector_type(8))) short short8;
typedef __attribute__((ext_vector_type(8))) unsigned short ushort8;
typedef __attribute__((ext_vector_type(4))) float f32x4;

__device__ inline unsigned short f2bf(float f) {
  unsigned u = __float_as_uint(f);
  u = u + 0x7fffu + ((u >> 16) & 1u);  // round-to-nearest-even
  return (unsigned short)(u >> 16);
}
__device__ inline float bf2f(unsigned short h) {
  return __uint_as_float(((unsigned)h) << 16);
}

// ===========================================================================
// CSR build: histogram -> 3-phase parallel scan -> fill
// ===========================================================================
__global__ __launch_bounds__(256) void hist_kernel(
    const int* __restrict__ ei, int E1, const int* __restrict__ ei2, int E2,
    int* __restrict__ deg1, int* __restrict__ deg2) {
  int stride = gridDim.x * blockDim.x;
  int Emax = max(E1, E2);
  for (int i = blockIdx.x * blockDim.x + threadIdx.x; i < Emax; i += stride) {
    if (i < E1) atomicAdd(&deg1[ei[E1 + i]], 1);
    if (i < E2) atomicAdd(&deg2[ei2[E2 + i]], 1);
  }
}

// Phase A: per-block sums. grid = 512 (arr = bid>>8, b = bid&255), N<=65536.
__global__ __launch_bounds__(256) void scan_partial_kernel(
    const int* __restrict__ deg1, const int* __restrict__ deg2, int N,
    int* __restrict__ bsum) {
  int arr = blockIdx.x >> 8;
  int b = blockIdx.x & 255;
  const int* deg = arr ? deg2 : deg1;
  int i = b * 256 + threadIdx.x;
  int v = (i < N) ? deg[i] : 0;
#pragma unroll
  for (int m = 1; m < 64; m <<= 1) v += __shfl_xor(v, m, 64);
  __shared__ int wsum[4];
  if ((threadIdx.x & 63) == 0) wsum[threadIdx.x >> 6] = v;
  __syncthreads();
  if (threadIdx.x == 0)
    bsum[blockIdx.x] = wsum[0] + wsum[1] + wsum[2] + wsum[3];
}

// Phase B: one block scans both 256-segments of bsum (exclusive, in place).
__global__ __launch_bounds__(512) void scan_bsum_kernel(
    int* __restrict__ bsum, int* __restrict__ off1, int* __restrict__ off2,
    int N) {
  __shared__ int sm[512];
  int t = threadIdx.x;
  int v = bsum[t];
  sm[t] = v;
  __syncthreads();
  for (int d = 1; d < 256; d <<= 1) {
    int val = ((t & 255) >= d) ? sm[t - d] : 0;
    __syncthreads();
    sm[t] += val;
    __syncthreads();
  }
  bsum[t] = sm[t] - v;            // exclusive block offset
  if (t == 255) off1[N] = sm[t];  // total array 1
  if (t == 511) off2[N] = sm[t];  // total array 2
}

// Phase C: in-block exclusive scan + block offset -> off[], cur[].
__global__ __launch_bounds__(256) void scan_fill_kernel(
    const int* __restrict__ deg1, const int* __restrict__ deg2,
    const int* __restrict__ bsum, int N,
    int* __restrict__ off1, int* __restrict__ cur1,
    int* __restrict__ off2, int* __restrict__ cur2) {
  int arr = blockIdx.x >> 8;
  int b = blockIdx.x & 255;
  const int* deg = arr ? deg2 : deg1;
  int* off = arr ? off2 : off1;
  int* cur = arr ? cur2 : cur1;
  int i = b * 256 + threadIdx.x;
  __shared__ int sm[256];
  int v = (i < N) ? deg[i] : 0;
  sm[threadIdx.x] = v;
  __syncthreads();
  for (int d = 1; d < 256; d <<= 1) {
    int val = (threadIdx.x >= d) ? sm[threadIdx.x - d] : 0;
    __syncthreads();
    sm[threadIdx.x] += val;
    __syncthreads();
  }
  int e = sm[threadIdx.x] - v + bsum[blockIdx.x];
  if (i < N) {
    off[i] = e;
    cur[i] = e;
  }
}

__global__ __launch_bounds__(256) void fill_kernel(
    const int* __restrict__ ei, int E1, const int* __restrict__ ei2, int E2,
    int* __restrict__ cur1, int* __restrict__ cur2,
    int* __restrict__ csr1, int* __restrict__ csr2) {
  int stride = gridDim.x * blockDim.x;
  int Emax = max(E1, E2);
  for (int i = blockIdx.x * blockDim.x + threadIdx.x; i < Emax; i += stride) {
    if (i < E1) {
      int d = ei[E1 + i];
      int p = atomicAdd(&cur1[d], 1);
      csr1[p] = ei[i];
    }
    if (i < E2) {
      int d = ei2[E2 + i];
      int p = atomicAdd(&cur2[d], 1);
      csr2[p] = ei2[i];
    }
  }
}

// ===========================================================================
// Conversions
// ===========================================================================
__global__ __launch_bounds__(256) void convert_x_kernel(
    const float* __restrict__ x, unsigned short* __restrict__ xb, long total8) {
  long t = (long)blockIdx.x * blockDim.x + threadIdx.x;
  if (t >= total8) return;
  const float4 f0 = *reinterpret_cast<const float4*>(x + t * 8);
  const float4 f1 = *reinterpret_cast<const float4*>(x + t * 8 + 4);
  ushort8 o;
  o[0] = f2bf(f0.x); o[1] = f2bf(f0.y); o[2] = f2bf(f0.z); o[3] = f2bf(f0.w);
  o[4] = f2bf(f1.x); o[5] = f2bf(f1.y); o[6] = f2bf(f1.z); o[7] = f2bf(f1.w);
  *reinterpret_cast<ushort8*>(xb + t * 8) = o;
}

// Bt[m][n][k] = W_m[k][n], bf16.  One block per (matrix, n) pair.
__global__ __launch_bounds__(256) void convert_w_kernel(
    const float* __restrict__ W0, const float* __restrict__ W1,
    const float* __restrict__ Wq, const float* __restrict__ Wk,
    const float* __restrict__ Wv, unsigned short* __restrict__ wt) {
  int m = blockIdx.x >> 8;
  int n = blockIdx.x & 255;
  int k = threadIdx.x;
  const float* W = m == 0 ? W0 : m == 1 ? W1 : m == 2 ? Wq : m == 3 ? Wk : Wv;
  wt[m * 65536 + n * 256 + k] = f2bf(W[k * 256 + n]);
}

// ===========================================================================
// agg[n] = sum_{e: dst=n} x[src_e]  (bf16 in, fp32 acc, bf16 out)
// ===========================================================================
__global__ __launch_bounds__(256) void gather_x_kernel(
    const unsigned short* __restrict__ xb, const int* __restrict__ off,
    const int* __restrict__ csr, int N, unsigned short* __restrict__ aggb) {
  int wid = blockIdx.x * 4 + (threadIdx.x >> 6);
  if (wid >= N) return;
  int lane = threadIdx.x & 63;
  int beg = off[wid], end = off[wid + 1];
  float ax = 0.f, ay = 0.f, az = 0.f, aw = 0.f;
  for (int j = beg; j < end; j++) {
    int s = csr[j];
    ushort4 xv = *reinterpret_cast<const ushort4*>(xb + (size_t)s * TD + lane * 4);
    ax += bf2f(xv.x); ay += bf2f(xv.y); az += bf2f(xv.z); aw += bf2f(xv.w);
  }
  ushort4 o;
  o.x = f2bf(ax); o.y = f2bf(ay); o.z = f2bf(az); o.w = f2bf(aw);
  *reinterpret_cast<ushort4*>(aggb + (size_t)wid * TD + lane * 4) = o;
}

// ===========================================================================
// out[n] -= sum_{e: d=n} (q[n].k[s_e]) * v[s_e]   (q,k,v bf16; out fp32)
// ===========================================================================
__global__ __launch_bounds__(256) void gather_attn_kernel(
    const unsigned short* __restrict__ qb, const unsigned short* __restrict__ kb,
    const unsigned short* __restrict__ vb, const int* __restrict__ off,
    const int* __restrict__ csr, int N, float* __restrict__ out) {
  int wid = blockIdx.x * 4 + (threadIdx.x >> 6);
  if (wid >= N) return;
  int lane = threadIdx.x & 63;
  ushort4 qv = *reinterpret_cast<const ushort4*>(qb + (size_t)wid * TD + lane * 4);
  float qx = bf2f(qv.x), qy = bf2f(qv.y), qz = bf2f(qv.z), qw = bf2f(qv.w);
  float* op = out + (size_t)wid * TD + lane * 4;
  float4 acc = *reinterpret_cast<const float4*>(op);
  int beg = off[wid], end = off[wid + 1];
  for (int j = beg; j < end; j++) {
    int s = csr[j];
    ushort4 kv = *reinterpret_cast<const ushort4*>(kb + (size_t)s * TD + lane * 4);
    float p = qx * bf2f(kv.x) + qy * bf2f(kv.y) + qz * bf2f(kv.z) + qw * bf2f(kv.w);
#pragma unroll
    for (int m = 1; m < 64; m <<= 1) p += __shfl_xor(p, m, 64);
    ushort4 vv = *reinterpret_cast<const ushort4*>(vb + (size_t)s * TD + lane * 4);
    acc.x -= p * bf2f(vv.x);
    acc.y -= p * bf2f(vv.y);
    acc.z -= p * bf2f(vv.z);
    acc.w -= p * bf2f(vv.w);
  }
  *reinterpret_cast<float4*>(op) = acc;
}

// ===========================================================================
// Fused MFMA GEMM.  grid = (8, ceil(M/128)).
//   sel = blockIdx.x; msel = sel>>1; n0 = (sel&1)*128; m0 = blockIdx.y*128
//   msel 0: out = [x | agg] @ [W0t ; W1t]   (K=512, fp32 out)
//   msel 1/2/3: q/k/v = x @ {Wqt,Wkt,Wvt}   (K=256, bf16 out)
// Tile 128x128, 4 waves (2x2 of 64x64), KSTEP=64, 16x16x32 bf16 MFMA.
// LDS staged via global_load_lds(16B) with XOR-(row&7) slot swizzle
// (pre-swizzled global source, linear LDS dest, swizzled ds_read).
// ===========================================================================
__global__ __launch_bounds__(256) void gemm_mfma(
    const unsigned short* __restrict__ xb, const unsigned short* __restrict__ aggb,
    const unsigned short* __restrict__ wt, float* __restrict__ out,
    unsigned short* __restrict__ qb, unsigned short* __restrict__ kb,
    unsigned short* __restrict__ vb, int M) {
  __shared__ __align__(16) unsigned short sA[128 * 64];
  __shared__ __align__(16) unsigned short sB[128 * 64];

  const int sel = blockIdx.x;
  const int msel = sel >> 1;
  const int n0 = (sel & 1) * 128;
  const int m0 = blockIdx.y * 128;

  const int tid = threadIdx.x;
  const int w = tid >> 6, l = tid & 63;
  const int lrow = l >> 3, lslot = l & 7;  // staging: 8 lanes/row, 8 slots/row
  const int wr = w >> 1, wc = w & 1;       // wave tile (64x64) coords

  f32x4 acc[4][4] = {};

  const int KTOT = (msel == 0) ? 512 : 256;

  for (int k0 = 0; k0 < KTOT; k0 += 64) {
    const unsigned short* Ap;
    const unsigned short* Bp;
    int ks;
    if (msel == 0) {
      if (k0 < 256) { Ap = xb;   Bp = wt;          ks = k0; }
      else          { Ap = aggb; Bp = wt + 65536;  ks = k0 - 256; }
    } else {
      Ap = xb; Bp = wt + (msel + 1) * 65536; ks = k0;
    }

    // ---- stage A tile [128][64] (rows m0..m0+127) ----
#pragma unroll
    for (int i = 0; i < 4; i++) {
      int row = w * 32 + i * 8 + lrow;          // row&7 == lrow
      int gr = m0 + row;
      if (gr >= M) gr = M - 1;                  // clamp (stores are guarded)
      int g = lslot ^ lrow;                     // inverse-swizzled k-group
      const unsigned short* src = Ap + (size_t)gr * TD + ks + g * 8;
      unsigned short* dst = sA + (w * 32 + i * 8) * 64;  // wave-uniform base
      __builtin_amdgcn_global_load_lds(
          (const __attribute__((address_space(1))) void*)src,
          (__attribute__((address_space(3))) void*)dst, 16, 0, 0);
    }
    // ---- stage B tile: Bt rows n0..n0+127 ----
#pragma unroll
    for (int i = 0; i < 4; i++) {
      int row = w * 32 + i * 8 + lrow;
      int g = lslot ^ lrow;
      const unsigned short* src = Bp + (size_t)(n0 + row) * TD + ks + g * 8;
      unsigned short* dst = sB + (w * 32 + i * 8) * 64;
      __builtin_amdgcn_global_load_lds(
          (const __attribute__((address_space(1))) void*)src,
          (__attribute__((address_space(3))) void*)dst, 16, 0, 0);
    }
    __syncthreads();

#pragma unroll
    for (int kk = 0; kk < 2; kk++) {
      short8 a[4], b[4];
#pragma unroll
      for (int m = 0; m < 4; m++) {
        int row = wr * 64 + m * 16 + (l & 15);
        int slot = (kk * 4 + (l >> 4)) ^ (row & 7);
        a[m] = *reinterpret_cast<const short8*>(&sA[row * 64 + slot * 8]);
      }
#pragma unroll
      for (int n = 0; n < 4; n++) {
        int row = wc * 64 + n * 16 + (l & 15);
        int slot = (kk * 4 + (l >> 4)) ^ (row & 7);
        b[n] = *reinterpret_cast<const short8*>(&sB[row * 64 + slot * 8]);
      }
#pragma unroll
      for (int m = 0; m < 4; m++)
#pragma unroll
        for (int n = 0; n < 4; n++)
          acc[m][n] =
              __builtin_amdgcn_mfma_f32_16x16x32_bf16(a[m], b[n], acc[m][n], 0, 0, 0);
    }
    __syncthreads();
  }

  // ---- store ----
  if (msel == 0) {
#pragma unroll
    for (int m = 0; m < 4; m++)
#pragma unroll
      for (int n = 0; n < 4; n++)
#pragma unroll
        for (int j = 0; j < 4; j++) {
          int r = m0 + wr * 64 + m * 16 + (l >> 4) * 4 + j;
          if (r < M)
            out[(size_t)r * TD + n0 + wc * 64 + n * 16 + (l & 15)] = acc[m][n][j];
        }
  } else {
    unsigned short* T = msel == 1 ? qb : msel == 2 ? kb : vb;
#pragma unroll
    for (int m = 0; m < 4; m++)
#pragma unroll
      for (int n = 0; n < 4; n++)
#pragma unroll
        for (int j = 0; j < 4; j++) {
          int r = m0 + wr * 64 + m * 16 + (l >> 4) * 4 + j;
          if (r < M)
            T[(size_t)r * TD + n0 + wc * 64 + n * 16 + (l & 15)] =
                f2bf(acc[m][n][j]);
        }
  }
}

// ===========================================================================
extern "C" void kernel_launch(void* const* d_in, const int* in_sizes, int n_in,
                              void* d_out, int out_size, void* d_ws,
                              size_t ws_size, hipStream_t stream) {
  const float* x  = (const float*)d_in[0];
  const int*   ei  = (const int*)d_in[1];
  const int*   ei2 = (const int*)d_in[2];
  const float* W0 = (const float*)d_in[3];
  const float* W1 = (const float*)d_in[4];
  const float* Wq = (const float*)d_in[5];
  const float* Wk = (const float*)d_in[6];
  const float* Wv = (const float*)d_in[7];

  const int N  = in_sizes[0] / TD;
  const int E1 = in_sizes[1] / 2;
  const int E2 = in_sizes[2] / 2;

  float* out = (float*)d_out;
  const size_t rowN = (size_t)N * TD;  // elements per [N,256] buffer

  // ---- workspace layout (bf16 buffers as ushort) ----
  char* p = (char*)d_ws;
  unsigned short* xb   = (unsigned short*)p; p += rowN * 2;
  unsigned short* aggb = (unsigned short*)p; p += rowN * 2;
  unsigned short* qb   = (unsigned short*)p; p += rowN * 2;
  unsigned short* kb   = (unsigned short*)p; p += rowN * 2;
  unsigned short* vb   = (unsigned short*)p; p += rowN * 2;
  unsigned short* wt   = (unsigned short*)p; p += 5 * 65536 * 2;
  int* off1 = (int*)p; p += (N + 1) * 4;
  int* cur1 = (int*)p; p += N * 4;
  int* off2 = (int*)p; p += (N + 1) * 4;
  int* cur2 = (int*)p; p += N * 4;
  int* csr1 = (int*)p; p += (size_t)E1 * 4;
  int* csr2 = (int*)p; p += (size_t)E2 * 4;
  int* deg1 = (int*)p; p += N * 4;
  int* deg2 = (int*)p; p += N * 4;
  int* bsum = (int*)p; p += 512 * 4;

  // 1. CSR build
  hipMemsetAsync(deg1, 0, (size_t)2 * N * sizeof(int), stream);  // deg1+deg2
  hist_kernel<<<1024, 256, 0, stream>>>(ei, E1, ei2, E2, deg1, deg2);
  scan_partial_kernel<<<512, 256, 0, stream>>>(deg1, deg2, N, bsum);
  scan_bsum_kernel<<<1, 512, 0, stream>>>(bsum, off1, off2, N);
  scan_fill_kernel<<<512, 256, 0, stream>>>(deg1, deg2, bsum, N, off1, cur1,
                                            off2, cur2);
  fill_kernel<<<1024, 256, 0, stream>>>(ei, E1, ei2, E2, cur1, cur2, csr1, csr2);

  // 2. conversions
  long total8 = rowN / 8;
  convert_x_kernel<<<(int)((total8 + 255) / 256), 256, 0, stream>>>(x, xb, total8);
  convert_w_kernel<<<5 * 256, 256, 0, stream>>>(W0, W1, Wq, Wk, Wv, wt);

  // 3. agg (bf16)
  gather_x_kernel<<<(N + 3) / 4, 256, 0, stream>>>(xb, off1, csr1, N, aggb);

  // 4. all five GEMMs in one dispatch
  dim3 grid(8, (N + 127) / 128);
  gemm_mfma<<<grid, 256, 0, stream>>>(xb, aggb, wt, out, qb, kb, vb, N);

  // 5. out -= gather(score * v)
  gather_attn_kernel<<<(N + 3) / 4, 256, 0, stream>>>(qb, kb, vb, off2, csr2, N, out);
}